// Round 12
// baseline (364.861 us; speedup 1.0000x reference)
//
#include <hip/hip_runtime.h>
#include <hip/hip_bf16.h>

#define HH_ 80
#define WW_ 80
#define CIN_ 256
#define NF_ 128
#define NPIX_ 6400
#define NTOK_ 12800
#define NELEM_ (NTOK_ * NF_)       // 1,638,400
#define NXEL_  (NTOK_ * CIN_)      // 3,276,800
#define KW_    2304                // 9*256  (conv3 K)
#define KWC_   1152                // 9*128  (conv_out K)
#define WEL_   294912

// attention tiling
#define KVS_    8                  // KV splits across blocks
#define KVB_    32                 // m per staged tile
#define MCHUNK_ 800                // NPIX_/KVS_
#define NIT_    25                 // MCHUNK_/KVB_

// fp32 conv outputs (phi/gv consumed by the transpose kernels)
__device__ float g_phi[NELEM_], g_gv[NELEM_];
// bf16 attention output (consumed by conv_out_mfma)
__device__ unsigned short g_aob[NELEM_];
// bf16 MFMA operands for attention
__device__ unsigned short g_th_hi[NELEM_], g_th_lo[NELEM_];
__device__ unsigned short g_phT_hi[NELEM_], g_phT_lo[NELEM_];
__device__ unsigned short g_gT[NELEM_];
// split-KV fp32 partials (unnormalized O, running m/l)
__device__ float g_po [KVS_ * NELEM_];          // 52 MB
__device__ float g_pml[KVS_ * NTOK_ * 2];
// bf16 hi/lo split of x, and transposed bf16 weights
// attn-conv weights: chunk-major [72 chunks][128 f][32 ch] (chunk = t*8+kc)
// conv_out weights:  chunk-major [36 chunks][256 f][32 ch] (chunk = t*4+kc)
__device__ unsigned short g_xh[NXEL_], g_xl[NXEL_];
__device__ unsigned short g_wtTh[WEL_], g_wtTl[WEL_];
__device__ unsigned short g_wpTh[WEL_], g_wpTl[WEL_];
__device__ unsigned short g_wgT[WEL_];
__device__ unsigned short g_wcT[WEL_];

__device__ __forceinline__ float b2f(unsigned short u) {
    union { unsigned int i; float f; } v; v.i = ((unsigned int)u) << 16; return v.f;
}
__device__ __forceinline__ unsigned short f2b(float f) {
    union { float f; unsigned int i; } v; v.f = f;
    unsigned int i = v.i;
    i += 0x7fffu + ((i >> 16) & 1u);   // RNE (finite only)
    return (unsigned short)(i >> 16);
}

typedef __attribute__((ext_vector_type(8))) short bf16x8;
typedef __attribute__((ext_vector_type(4))) float f32x4;

__device__ __forceinline__ f32x4 mfma16(bf16x8 a, bf16x8 b, f32x4 c) {
    return __builtin_amdgcn_mfma_f32_16x16x32_bf16(a, b, c, 0, 0, 0);
}

// ---------------------------------------------------------------------------
// prep_x: fp32 x -> bf16 hi/lo split
// ---------------------------------------------------------------------------
__global__ __launch_bounds__(256) void prep_x(const float* __restrict__ x)
{
    const int i = (blockIdx.x * 256 + threadIdx.x) * 4;
    if (i >= NXEL_) return;
    const float4 v = *(const float4*)(x + i);
    ushort4 hi, lo;
    hi.x = f2b(v.x); lo.x = f2b(v.x - b2f(hi.x));
    hi.y = f2b(v.y); lo.y = f2b(v.y - b2f(hi.y));
    hi.z = f2b(v.z); lo.z = f2b(v.z - b2f(hi.z));
    hi.w = f2b(v.w); lo.w = f2b(v.w - b2f(hi.w));
    *(ushort4*)(g_xh + i) = hi;
    *(ushort4*)(g_xl + i) = lo;
}

// ---------------------------------------------------------------------------
// prep_w: attn-conv weights -> chunk-major [72][128][32] bf16 (hi/lo for
// w_theta/w_phi); conv_out weights -> chunk-major [36][256][32].
// ---------------------------------------------------------------------------
__global__ __launch_bounds__(256) void prep_w(
    const float* __restrict__ wt, const float* __restrict__ wp,
    const float* __restrict__ wg, const float* __restrict__ wc)
{
    const int i = blockIdx.x * 256 + threadIdx.x;
    if (i >= WEL_) return;
    {
        const int t  = i / (256 * 128);
        const int r  = i % (256 * 128);
        const int ci = r >> 7;
        const int f  = r & 127;
        const size_t d = (size_t)(t * 8 + (ci >> 5)) * 4096
                       + (size_t)f * 32 + (ci & 31);
        const float tv = wt[i];
        const unsigned short th = f2b(tv);
        g_wtTh[d] = th; g_wtTl[d] = f2b(tv - b2f(th));
        const float pv = wp[i];
        const unsigned short ph = f2b(pv);
        g_wpTh[d] = ph; g_wpTl[d] = f2b(pv - b2f(ph));
        g_wgT[d] = f2b(wg[i]);
    }
    {
        const int t  = i / (128 * 256);
        const int r  = i % (128 * 256);
        const int ci = r >> 8;
        const int f  = r & 255;
        const size_t d = (size_t)(t * 4 + (ci >> 5)) * 8192
                       + (size_t)f * 32 + (ci & 31);
        g_wcT[d] = f2b(wc[i]);
    }
}

// ---------------------------------------------------------------------------
// conv3_mfma v4 (verified r10): LDS-staged implicit-GEMM 3x3 conv, 3 heads
// fused, theta hi/lo pack fused into the epilogue.
// ---------------------------------------------------------------------------
__global__ __launch_bounds__(512) void conv3_mfma()
{
    __shared__ __align__(16) unsigned short w_lds[5][128][40];   // 50 KB
    __shared__ __align__(16) unsigned short x_lds[64][2][40];    // 10 KB

    const int tid  = threadIdx.x;
    const int wv   = tid >> 6;
    const int lane = tid & 63;
    const int quad = lane >> 4;
    const int ll   = lane & 15;
    const int wp   = wv >> 2;          // pixel group 0..1
    const int wf   = wv & 3;           // filter group 0..3
    const int P0   = blockIdx.x * 64;
    const int fb   = wf * 32;

    // staging thread maps
    const int sxp = tid >> 3;          // x: pixel 0..63
    const int sxh = (tid >> 2) & 1;    // x: hi/lo
    const int sxc = (tid & 3) * 8;     // x: ch offset
    const int swf = tid >> 2;          // w: filter 0..127
    const int swc = (tid & 3) * 8;     // w: ch offset

    // x staging source pixel coords
    const int sp  = P0 + sxp;
    const int spb = sp / NPIX_;
    const int spl = sp % NPIX_;
    const int sph = spl / WW_;
    const int spw = spl % WW_;

    const bf16x8 ZV = {0,0,0,0,0,0,0,0};
    bf16x8 rx, rw0, rw1, rw2, rw3, rw4;

#define C3_STAGE_LOAD(s)                                                      \
    {                                                                         \
        const int t_ = (s) >> 3, kc_ = (s) & 7;                               \
        const int hh_ = sph + t_ / 3 - 1, ww_ = spw + t_ % 3 - 1;             \
        if (hh_ >= 0 && hh_ < HH_ && ww_ >= 0 && ww_ < WW_) {                 \
            const size_t src_ = ((size_t)spb * NPIX_ + hh_ * WW_ + ww_) * CIN_\
                                + kc_ * 32 + sxc;                             \
            rx = sxh ? *(const bf16x8*)(g_xl + src_)                          \
                     : *(const bf16x8*)(g_xh + src_);                         \
        } else rx = ZV;                                                       \
        const size_t ws_ = (size_t)(s) * 4096 + (size_t)swf * 32 + swc;       \
        rw0 = *(const bf16x8*)(g_wtTh + ws_);                                 \
        rw1 = *(const bf16x8*)(g_wtTl + ws_);                                 \
        rw2 = *(const bf16x8*)(g_wpTh + ws_);                                 \
        rw3 = *(const bf16x8*)(g_wpTl + ws_);                                 \
        rw4 = *(const bf16x8*)(g_wgT  + ws_);                                 \
    }

#define C3_STAGE_WRITE()                                                      \
    {                                                                         \
        *(bf16x8*)(&x_lds[sxp][sxh][sxc]) = rx;                               \
        *(bf16x8*)(&w_lds[0][swf][swc]) = rw0;                                \
        *(bf16x8*)(&w_lds[1][swf][swc]) = rw1;                                \
        *(bf16x8*)(&w_lds[2][swf][swc]) = rw2;                                \
        *(bf16x8*)(&w_lds[3][swf][swc]) = rw3;                                \
        *(bf16x8*)(&w_lds[4][swf][swc]) = rw4;                                \
    }

    f32x4 aT[2][2], aP[2][2], aG[2][2];   // [pt][ft]
    #pragma unroll
    for (int pt = 0; pt < 2; ++pt)
        #pragma unroll
        for (int ft = 0; ft < 2; ++ft) {
            aT[pt][ft] = (f32x4){0.f,0.f,0.f,0.f};
            aP[pt][ft] = (f32x4){0.f,0.f,0.f,0.f};
            aG[pt][ft] = (f32x4){0.f,0.f,0.f,0.f};
        }

    C3_STAGE_LOAD(0);
    C3_STAGE_WRITE();
    __syncthreads();

    for (int s = 0; s < 72; ++s) {
        const bool pf = (s + 1 < 72);
        if (pf) C3_STAGE_LOAD(s + 1);

        bf16x8 xa[2][2];   // [pt][hi/lo]
        #pragma unroll
        for (int pt = 0; pt < 2; ++pt) {
            const int px = wp * 32 + pt * 16 + ll;
            xa[pt][0] = *(const bf16x8*)(&x_lds[px][0][quad * 8]);
            xa[pt][1] = *(const bf16x8*)(&x_lds[px][1][quad * 8]);
        }
        #pragma unroll
        for (int ft = 0; ft < 2; ++ft) {
            const int f = fb + ft * 16 + ll;
            const bf16x8 tH = *(const bf16x8*)(&w_lds[0][f][quad * 8]);
            const bf16x8 tL = *(const bf16x8*)(&w_lds[1][f][quad * 8]);
            const bf16x8 pH = *(const bf16x8*)(&w_lds[2][f][quad * 8]);
            const bf16x8 pL = *(const bf16x8*)(&w_lds[3][f][quad * 8]);
            const bf16x8 gB = *(const bf16x8*)(&w_lds[4][f][quad * 8]);
            #pragma unroll
            for (int pt = 0; pt < 2; ++pt) {
                aT[pt][ft] = mfma16(xa[pt][0], tH, aT[pt][ft]);
                aT[pt][ft] = mfma16(xa[pt][0], tL, aT[pt][ft]);
                aT[pt][ft] = mfma16(xa[pt][1], tH, aT[pt][ft]);
                aP[pt][ft] = mfma16(xa[pt][0], pH, aP[pt][ft]);
                aP[pt][ft] = mfma16(xa[pt][0], pL, aP[pt][ft]);
                aP[pt][ft] = mfma16(xa[pt][1], pH, aP[pt][ft]);
                aG[pt][ft] = mfma16(xa[pt][0], gB, aG[pt][ft]);
            }
        }

        __syncthreads();               // all reads of this tile done
        if (pf) C3_STAGE_WRITE();      // vmcnt wait folds in here
        __syncthreads();               // next tile visible
    }

    #pragma unroll
    for (int pt = 0; pt < 2; ++pt)
        #pragma unroll
        for (int ft = 0; ft < 2; ++ft) {
            const int f = fb + ft * 16 + ll;
            #pragma unroll
            for (int r = 0; r < 4; ++r) {
                const size_t n = P0 + wp * 32 + pt * 16 + quad * 4 + r;
                const float tv = aT[pt][ft][r];
                const unsigned short th = f2b(tv);
                g_th_hi[n * NF_ + f] = th;
                g_th_lo[n * NF_ + f] = f2b(tv - b2f(th));
                g_phi[n * NF_ + f] = aP[pt][ft][r];
                g_gv [n * NF_ + f] = aG[pt][ft][r];
            }
        }
#undef C3_STAGE_LOAD
#undef C3_STAGE_WRITE
}

// ---------------------------------------------------------------------------
// prep_tr_phi: LDS-tiled transpose of phi -> phT hi/lo. (verified r10)
// ---------------------------------------------------------------------------
__global__ __launch_bounds__(256) void prep_tr_phi()
{
    __shared__ float tile[128][65];    // 33.3 KB

    const int tid = threadIdx.x;
    const int b   = blockIdx.x & 1;
    const int mp0 = (blockIdx.x >> 1) * 64;
    const size_t boff = (size_t)b * (NPIX_ * NF_);

    // read: 128 cp-rows x 64 mp-cols, coalesced float4
    const int rr = tid >> 1;           // cp 0..127
    const int rc = (tid & 1) * 32;     // mp col group
    #pragma unroll
    for (int k = 0; k < 8; ++k) {
        const float4 v = *(const float4*)(
            g_phi + boff + (size_t)rr * NPIX_ + mp0 + rc + k * 4);
        tile[rr][rc + k * 4 + 0] = v.x;
        tile[rr][rc + k * 4 + 1] = v.y;
        tile[rr][rc + k * 4 + 2] = v.z;
        tile[rr][rc + k * 4 + 3] = v.w;
    }
    __syncthreads();

    // write: 64 mp-rows x 128 cp-cols
    const int ml = tid >> 2;           // mp local 0..63
    const int cg = (tid & 3) * 32;     // cp group
    __attribute__((aligned(16))) unsigned short hi[32], lo[32];
    #pragma unroll
    for (int k = 0; k < 32; ++k) {
        const float v = tile[cg + k][ml];
        hi[k] = f2b(v);
        lo[k] = f2b(v - b2f(hi[k]));
    }
    unsigned short* dh = g_phT_hi + boff + (size_t)(mp0 + ml) * NF_ + cg;
    unsigned short* dl = g_phT_lo + boff + (size_t)(mp0 + ml) * NF_ + cg;
    #pragma unroll
    for (int k = 0; k < 32; k += 8) {
        *(uint4*)(dh + k) = *(const uint4*)(hi + k);
        *(uint4*)(dl + k) = *(const uint4*)(lo + k);
    }
}

// ---------------------------------------------------------------------------
// prep_tr_g: LDS-tiled transpose of g -> gT. (verified r10)
// ---------------------------------------------------------------------------
__global__ __launch_bounds__(256) void prep_tr_g()
{
    __shared__ float tile[64][129];    // 33 KB

    const int tid = threadIdx.x;
    const int b   = blockIdx.x & 1;
    const int nl0 = (blockIdx.x >> 1) * 64;
    const size_t boff = (size_t)b * (NPIX_ * NF_);

    // read: 64 nl-rows x 128 c-cols, coalesced float4
    const int rn = tid >> 2;           // nl local 0..63
    const int rc = (tid & 3) * 32;     // c col group
    #pragma unroll
    for (int k = 0; k < 8; ++k) {
        const float4 v = *(const float4*)(
            g_gv + boff + (size_t)(nl0 + rn) * NF_ + rc + k * 4);
        tile[rn][rc + k * 4 + 0] = v.x;
        tile[rn][rc + k * 4 + 1] = v.y;
        tile[rn][rc + k * 4 + 2] = v.z;
        tile[rn][rc + k * 4 + 3] = v.w;
    }
    __syncthreads();

    // write: 128 c-rows x 64 nl-cols
    const int cl = tid >> 1;           // c local 0..127
    const int ng = (tid & 1) * 32;     // nl group
    __attribute__((aligned(16))) unsigned short gv[32];
    #pragma unroll
    for (int k = 0; k < 32; ++k)
        gv[k] = f2b(tile[ng + k][cl]);
    unsigned short* dst = g_gT + boff + (size_t)cl * NPIX_ + nl0 + ng;
    #pragma unroll
    for (int k = 0; k < 32; k += 8)
        *(uint4*)(dst + k) = *(const uint4*)(gv + k);
}

// ---------------------------------------------------------------------------
// attn_mfma v10: v7 (verified 151.8us) + T2 XOR-swizzle on the K tiles.
//
// v9's double-buffer regressed (60KB LDS halved residency: occupancy
// 26->19%, 161us) -- the 32KB/84VGPR point is resource-critical; only
// resource-NEUTRAL changes can win. Bank arithmetic for v7's K reads
// (stride 136 shorts = 272B = 4 banks): bank-start = 4*(ll+quad) mod 32
// -> 8 lanes per 16B bank-group per ds_read_b128; the 1.98e7 conflict
// cycles (~21% of dispatch) are dominated by the 16 K-reads/iter. Fix:
// [32][128] linear (stride = 0 banks) + involution slot ^= (row&7) on
// BOTH sides (write: reg-staged so we control the address; read:
// slot=(kk*4+quad)^(ll&7), row&7==ll&7). Per (kk,quad): ll=0..7 hit 8
// distinct slots -> 2 lanes/slot -> free (m136). LDS 32.8->31.1 KB.
// ---------------------------------------------------------------------------
__global__ __launch_bounds__(256) void attn_mfma()
{
    __shared__ __align__(16) unsigned short kh_lds[KVB_][128];  // 8 KB
    __shared__ __align__(16) unsigned short kl_lds[KVB_][128];  // 8 KB
    __shared__ __align__(16) unsigned short v_lds[NF_][40];     // 10 KB
    // per-wave: cols 0..31 = P rows [q][m]; cols 32..39 of rows 0..3 = al[16]
    __shared__ __align__(16) short p_lds[4][16 * 40];           // 5.1 KB

    const int tid  = threadIdx.x;
    const int w    = tid >> 6;
    const int lane = tid & 63;
    const int quad = lane >> 4;
    const int ll   = lane & 15;

    const int cid = blockIdx.x & 15;        // (b,kvs): round-robin over XCDs
    const int qw  = blockIdx.x >> 4;        // 0..99
    const int b   = cid >> 3;
    const int kvs = cid & 7;
    const int R0  = b * NPIX_ + qw * 64;    // 64 Q rows per block
    const int m_start = kvs * MCHUNK_;      // within-batch m offset

    const unsigned short* phH = g_phT_hi + (size_t)b * (NPIX_ * NF_);
    const unsigned short* phL = g_phT_lo + (size_t)b * (NPIX_ * NF_);
    const unsigned short* gT  = g_gT    + (size_t)b * (NPIX_ * NF_);

    // theta fragments for this wave's 16 rows (B operand: col q=ll)
    bf16x8 aH[4], aL[4];
    #pragma unroll
    for (int kk = 0; kk < 4; ++kk) {
        const size_t off = (size_t)(R0 + w * 16 + ll) * 128 + kk * 32 + quad * 8;
        aH[kk] = *(const bf16x8*)(g_th_hi + off);
        aL[kk] = *(const bf16x8*)(g_th_lo + off);
    }

    f32x4 acc[8];
    #pragma unroll
    for (int t = 0; t < 8; ++t) acc[t] = (f32x4){0.f, 0.f, 0.f, 0.f};
    float mi = -1e30f, li = 0.f;            // per-lane: q = ll

    const int kr0 = tid >> 4;            // K rows 0..15 (and +16)
    // swizzled K slot for staging: logical slot (tid&15), row kr0
    // ((kr0+16)&7 == kr0&7 -> same swizzle for both rows)
    const int ksl = (((tid & 15) ^ (kr0 & 7)) * 8);
    const int kc0 = (tid & 15) * 8;      // K col elems (global src)
    const int vr0 = tid >> 2;            // V rows 0..63 (and +64)
    const int vm0 = (tid & 3) * 8;       // V m elems
    const int sx  = ll & 7;              // read-side swizzle key (== mrow&7)

    bf16x8 skh0, skh1, skl0, skl1, sv0, sv1;

    {
        const int m0 = m_start;
        skh0 = *(const bf16x8*)(phH + (size_t)(m0 + kr0) * 128 + kc0);
        skh1 = *(const bf16x8*)(phH + (size_t)(m0 + kr0 + 16) * 128 + kc0);
        skl0 = *(const bf16x8*)(phL + (size_t)(m0 + kr0) * 128 + kc0);
        skl1 = *(const bf16x8*)(phL + (size_t)(m0 + kr0 + 16) * 128 + kc0);
        sv0  = *(const bf16x8*)(gT + (size_t)vr0 * NPIX_ + m0 + vm0);
        sv1  = *(const bf16x8*)(gT + (size_t)(vr0 + 64) * NPIX_ + m0 + vm0);
        *(bf16x8*)(&kh_lds[kr0][ksl])      = skh0;
        *(bf16x8*)(&kh_lds[kr0 + 16][ksl]) = skh1;
        *(bf16x8*)(&kl_lds[kr0][ksl])      = skl0;
        *(bf16x8*)(&kl_lds[kr0 + 16][ksl]) = skl1;
        *(bf16x8*)(&v_lds[vr0][vm0])       = sv0;
        *(bf16x8*)(&v_lds[vr0 + 64][vm0])  = sv1;
    }
    __syncthreads();

    short* pl = &p_lds[w][0];

    for (int it = 0; it < NIT_; ++it) {
        const bool pf = (it + 1 < NIT_);
        if (pf) {
            const int m0 = m_start + (it + 1) * KVB_;
            skh0 = *(const bf16x8*)(phH + (size_t)(m0 + kr0) * 128 + kc0);
            skh1 = *(const bf16x8*)(phH + (size_t)(m0 + kr0 + 16) * 128 + kc0);
            skl0 = *(const bf16x8*)(phL + (size_t)(m0 + kr0) * 128 + kc0);
            skl1 = *(const bf16x8*)(phL + (size_t)(m0 + kr0 + 16) * 128 + kc0);
            sv0  = *(const bf16x8*)(gT + (size_t)vr0 * NPIX_ + m0 + vm0);
            sv1  = *(const bf16x8*)(gT + (size_t)(vr0 + 64) * NPIX_ + m0 + vm0);
        }

        // ---- S = K * theta^T (swapped): s[mt][r] = S[m=mt*16+quad*4+r][q=ll]
        f32x4 s[2];
        #pragma unroll
        for (int mt = 0; mt < 2; ++mt) {
            f32x4 s0 = (f32x4){0.f,0.f,0.f,0.f};
            const int mrow = mt * 16 + ll;
            #pragma unroll
            for (int kk = 0; kk < 4; ++kk) {
                const int kcol = ((kk * 4 + quad) ^ sx) * 8;   // swizzled slot
                const bf16x8 bH = *(const bf16x8*)(&kh_lds[mrow][kcol]);
                const bf16x8 bL = *(const bf16x8*)(&kl_lds[mrow][kcol]);
                s0 = mfma16(bH, aH[kk], s0);
                s0 = mfma16(bL, aH[kk], s0);
                s0 = mfma16(bH, aL[kk], s0);
            }
            s[mt] = s0;
        }

        // ---- per-lane online softmax for q = ll ---------------------------
        float cm = fmaxf(fmaxf(fmaxf(s[0][0], s[0][1]), fmaxf(s[0][2], s[0][3])),
                         fmaxf(fmaxf(s[1][0], s[1][1]), fmaxf(s[1][2], s[1][3])));
        cm = fmaxf(cm, __shfl_xor(cm, 16));
        cm = fmaxf(cm, __shfl_xor(cm, 32));
        // defer-rescale (T13): wave-uniform skip when no q-row grows > THR
        const bool nog = __all(cm <= mi + 4.0f);
        if (!nog) {
            const float nm = fmaxf(mi, cm);
            const float al = __expf(mi - nm);
            mi = nm;
            li *= al;
            if (quad == 0)
                ((float*)(pl + (ll >> 2) * 40 + 32))[ll & 3] = al;
        }
        float ssum = 0.f;
        #pragma unroll
        for (int mt = 0; mt < 2; ++mt)
            #pragma unroll
            for (int r = 0; r < 4; ++r) {
                const float e = __expf(s[mt][r] - mi);
                s[mt][r] = e; ssum += e;
            }
        ssum += __shfl_xor(ssum, 16);
        ssum += __shfl_xor(ssum, 32);
        li += ssum;

        // ---- P pack via v_cvt_pk_bf16_f32 (T12): 2 uint stores ------------
        #pragma unroll
        for (int mt = 0; mt < 2; ++mt) {
            unsigned int c0_, c1_;
            asm("v_cvt_pk_bf16_f32 %0, %1, %2"
                : "=v"(c0_) : "v"(s[mt][0]), "v"(s[mt][1]));
            asm("v_cvt_pk_bf16_f32 %0, %1, %2"
                : "=v"(c1_) : "v"(s[mt][2]), "v"(s[mt][3]));
            *(uint2*)(pl + ll * 40 + mt * 16 + quad * 4) = make_uint2(c0_, c1_);
        }

        // ---- rescale acc rows with their al (skipped when deferred) -------
        if (!nog) {
            const float* alp = (const float*)(pl + quad * 40 + 32);
            #pragma unroll
            for (int r = 0; r < 4; ++r) {
                const float av = alp[r];
                #pragma unroll
                for (int t = 0; t < 8; ++t) acc[t][r] *= av;
            }
        }

        const bf16x8 pa = *(const bf16x8*)(pl + ll * 40 + quad * 8);

        // ---- PV: 8 channel-tiles, k=32 ------------------------------------
        #pragma unroll
        for (int ct = 0; ct < 8; ++ct) {
            const bf16x8 gb = *(const bf16x8*)(&v_lds[ct * 16 + ll][quad * 8]);
            acc[ct] = mfma16(pa, gb, acc[ct]);
        }

        __syncthreads();
        if (pf) {
            *(bf16x8*)(&kh_lds[kr0][ksl])      = skh0;
            *(bf16x8*)(&kh_lds[kr0 + 16][ksl]) = skh1;
            *(bf16x8*)(&kl_lds[kr0][ksl])      = skl0;
            *(bf16x8*)(&kl_lds[kr0 + 16][ksl]) = skl1;
            *(bf16x8*)(&v_lds[vr0][vm0])       = sv0;
            *(bf16x8*)(&v_lds[vr0 + 64][vm0])  = sv1;
        }
        __syncthreads();
    }

    const int row0 = R0 + w * 16;
    #pragma unroll
    for (int ct = 0; ct < 8; ++ct)
        #pragma unroll
        for (int r = 0; r < 4; ++r)
            g_po[((size_t)kvs * NTOK_ + row0 + quad * 4 + r) * NF_ + ct * 16 + ll]
                = acc[ct][r];
    if (quad == 0) {
        const size_t mlidx = ((size_t)kvs * NTOK_ + row0 + ll) * 2;
        g_pml[mlidx]     = mi;
        g_pml[mlidx + 1] = li;
    }
}

// ---------------------------------------------------------------------------
// merge_attn: combine KVS_ fp32 partials -> normalized bf16 g_aob
// ---------------------------------------------------------------------------
__global__ __launch_bounds__(256) void merge_attn()
{
    const int idx = blockIdx.x * 256 + threadIdx.x;   // NTOK_*16 threads
    const int row = idx >> 4;
    const int c0  = (idx & 15) * 8;

    float m[KVS_], l[KVS_];
    #pragma unroll
    for (int s = 0; s < KVS_; ++s) {
        const size_t mlidx = ((size_t)s * NTOK_ + row) * 2;
        m[s] = g_pml[mlidx];
        l[s] = g_pml[mlidx + 1];
    }
    float M = m[0];
    #pragma unroll
    for (int s = 1; s < KVS_; ++s) M = fmaxf(M, m[s]);
    float a[KVS_], L = 0.f;
    #pragma unroll
    for (int s = 0; s < KVS_; ++s) {
        a[s] = __expf(m[s] - M);
        L += a[s] * l[s];
    }
    const float inv = 1.f / L;

    float o[8];
    #pragma unroll
    for (int j = 0; j < 8; ++j) o[j] = 0.f;
    #pragma unroll
    for (int s = 0; s < KVS_; ++s) {
        const float* p = g_po + ((size_t)s * NTOK_ + row) * NF_ + c0;
        const float4 p0 = *(const float4*)(p);
        const float4 p1 = *(const float4*)(p + 4);
        o[0] += a[s] * p0.x; o[1] += a[s] * p0.y;
        o[2] += a[s] * p0.z; o[3] += a[s] * p0.w;
        o[4] += a[s] * p1.x; o[5] += a[s] * p1.y;
        o[6] += a[s] * p1.z; o[7] += a[s] * p1.w;
    }
    unsigned short tmp[8];
    #pragma unroll
    for (int j = 0; j < 8; ++j) tmp[j] = f2b(o[j] * inv);
    unsigned short* dst = g_aob + (size_t)row * NF_ + c0;
    *(ushort4*)(dst)     = make_ushort4(tmp[0], tmp[1], tmp[2], tmp[3]);
    *(ushort4*)(dst + 4) = make_ushort4(tmp[4], tmp[5], tmp[6], tmp[7]);
}

// ---------------------------------------------------------------------------
// conv_out_mfma v3 (r11): LDS-staged implicit-GEMM 3x3 conv + fp32 residual,
// double-buffered (one barrier/step). Grid 200 = 1 block/CU -> LDS growth
// is free; r11 decomposition suggests ~3-4us gain vs v2.
// ---------------------------------------------------------------------------
__global__ __launch_bounds__(512) void conv_out_mfma(
    const float* __restrict__ x, float* __restrict__ out)
{
    __shared__ __align__(16) unsigned short w_lds[2][256][40];   // 40 KB
    __shared__ __align__(16) unsigned short a_lds[2][64][40];    // 10 KB

    const int tid  = threadIdx.x;
    const int wv   = tid >> 6;
    const int lane = tid & 63;
    const int quad = lane >> 4;
    const int ll   = lane & 15;
    const int wp   = wv >> 2;            // pixel group 0..1
    const int wf   = wv & 3;             // filter group 0..3 (64 f each)
    const int P0   = blockIdx.x * 64;
    const int fb   = wf * 64;

    const int swf = tid >> 1;            // W: filter 0..255
    const int swc = (tid & 1) * 16;      // W: ch offset 0/16
    const int sap = tid >> 2;            // A: pixel idx (valid when tid<256)
    const int sac = (tid & 3) * 8;       // A: ch offset

    const int sp  = P0 + sap;
    const int spb = sp / NPIX_;
    const int spl = sp % NPIX_;
    const int sph = spl / WW_;
    const int spw = spl % WW_;

    const bf16x8 ZV = {0,0,0,0,0,0,0,0};
    bf16x8 ra, rwA, rwB;

#define CO_STAGE_LOAD(s)                                                      \
    {                                                                         \
        const int t_ = (s) >> 2, kc_ = (s) & 3;                               \
        if (tid < 256) {                                                      \
            const int hh_ = sph + t_ / 3 - 1, ww_ = spw + t_ % 3 - 1;         \
            if (hh_ >= 0 && hh_ < HH_ && ww_ >= 0 && ww_ < WW_) {             \
                const size_t src_ = ((size_t)spb * NPIX_ + hh_ * WW_ + ww_)   \
                                    * NF_ + kc_ * 32 + sac;                   \
                ra = *(const bf16x8*)(g_aob + src_);                          \
            } else ra = ZV;                                                   \
        }                                                                     \
        const size_t ws_ = (size_t)(s) * 8192 + (size_t)swf * 32 + swc;       \
        rwA = *(const bf16x8*)(g_wcT + ws_);                                  \
        rwB = *(const bf16x8*)(g_wcT + ws_ + 8);                              \
    }

#define CO_STAGE_WRITE(bi)                                                    \
    {                                                                         \
        if (tid < 256) *(bf16x8*)(&a_lds[bi][sap][sac]) = ra;                 \
        *(bf16x8*)(&w_lds[bi][swf][swc])     = rwA;                           \
        *(bf16x8*)(&w_lds[bi][swf][swc + 8]) = rwB;                           \
    }

    f32x4 acc[2][4];
    #pragma unroll
    for (int pt = 0; pt < 2; ++pt)
        #pragma unroll
        for (int ft = 0; ft < 4; ++ft) acc[pt][ft] = (f32x4){0.f,0.f,0.f,0.f};

    CO_STAGE_LOAD(0);
    CO_STAGE_WRITE(0);
    __syncthreads();

    int cur = 0;
    for (int s = 0; s < 36; ++s) {
        const bool pf = (s + 1 < 36);
        if (pf) CO_STAGE_LOAD(s + 1);

        bf16x8 a[2];
        #pragma unroll
        for (int pt = 0; pt < 2; ++pt)
            a[pt] = *(const bf16x8*)(&a_lds[cur][wp * 32 + pt * 16 + ll][quad * 8]);
        #pragma unroll
        for (int ft = 0; ft < 4; ++ft) {
            const bf16x8 bw = *(const bf16x8*)(&w_lds[cur][fb + ft * 16 + ll][quad * 8]);
            #pragma unroll
            for (int pt = 0; pt < 2; ++pt)
                acc[pt][ft] = mfma16(a[pt], bw, acc[pt][ft]);
        }

        if (pf) CO_STAGE_WRITE(cur ^ 1);
        __syncthreads();
        cur ^= 1;
    }

    #pragma unroll
    for (int pt = 0; pt < 2; ++pt)
        #pragma unroll
        for (int ft = 0; ft < 4; ++ft) {
            const int f = fb + ft * 16 + ll;
            #pragma unroll
            for (int r = 0; r < 4; ++r) {
                const size_t n = P0 + wp * 32 + pt * 16 + quad * 4 + r;
                const size_t oi = n * CIN_ + f;
                out[oi] = x[oi] + acc[pt][ft][r];
            }
        }
#undef CO_STAGE_LOAD
#undef CO_STAGE_WRITE
}

// ---------------------------------------------------------------------------
extern "C" void kernel_launch(void* const* d_in, const int* in_sizes, int n_in,
                              void* d_out, int out_size, void* d_ws, size_t ws_size,
                              hipStream_t stream)
{
    const float* x  = (const float*)d_in[0];
    const float* wt = (const float*)d_in[1];
    const float* wp = (const float*)d_in[2];
    const float* wg = (const float*)d_in[3];
    const float* wc = (const float*)d_in[4];
    float* out = (float*)d_out;

    prep_x<<<NXEL_ / 4 / 256, 256, 0, stream>>>(x);
    prep_w<<<(WEL_ + 255) / 256, 256, 0, stream>>>(wt, wp, wg, wc);
    conv3_mfma<<<NTOK_ / 64, 512, 0, stream>>>();
    prep_tr_phi<<<2 * (NPIX_ / 64), 256, 0, stream>>>();
    prep_tr_g<<<2 * (NPIX_ / 64), 256, 0, stream>>>();
    attn_mfma<<<(NTOK_ / 64) * KVS_, 256, 0, stream>>>();
    merge_attn<<<NTOK_ * 16 / 256, 256, 0, stream>>>();
    conv_out_mfma<<<NTOK_ / 64, 512, 0, stream>>>(x, out);
}

// Round 13
// 347.880 us; speedup vs baseline: 1.0488x; 1.0488x over previous
//
#include <hip/hip_runtime.h>
#include <hip/hip_bf16.h>

#define HH_ 80
#define WW_ 80
#define CIN_ 256
#define NF_ 128
#define NPIX_ 6400
#define NTOK_ 12800
#define NELEM_ (NTOK_ * NF_)       // 1,638,400
#define NXEL_  (NTOK_ * CIN_)      // 3,276,800
#define KW_    2304                // 9*256  (conv3 K)
#define KWC_   1152                // 9*128  (conv_out K)
#define WEL_   294912

// attention tiling
#define KVS_    8                  // KV splits across blocks
#define KVB_    32                 // m per staged tile
#define MCHUNK_ 800                // NPIX_/KVS_
#define NIT_    25                 // MCHUNK_/KVB_

// fp32 conv outputs (phi/gv consumed by the transpose kernels)
__device__ float g_phi[NELEM_], g_gv[NELEM_];
// bf16 attention output (consumed by conv_out_mfma)
__device__ unsigned short g_aob[NELEM_];
// bf16 MFMA operands for attention
__device__ unsigned short g_th_hi[NELEM_], g_th_lo[NELEM_];
__device__ unsigned short g_phT_hi[NELEM_], g_phT_lo[NELEM_];
__device__ unsigned short g_gT[NELEM_];
// split-KV fp32 partials (unnormalized O, running m/l)
__device__ float g_po [KVS_ * NELEM_];          // 52 MB
__device__ float g_pml[KVS_ * NTOK_ * 2];
// bf16 hi/lo split of x, and transposed bf16 weights
// attn-conv weights: chunk-major [72 chunks][128 f][32 ch] (chunk = t*8+kc)
// conv_out weights:  chunk-major [36 chunks][256 f][32 ch] (chunk = t*4+kc)
__device__ unsigned short g_xh[NXEL_], g_xl[NXEL_];
__device__ unsigned short g_wtTh[WEL_], g_wtTl[WEL_];
__device__ unsigned short g_wpTh[WEL_], g_wpTl[WEL_];
__device__ unsigned short g_wgT[WEL_];
__device__ unsigned short g_wcT[WEL_];

__device__ __forceinline__ float b2f(unsigned short u) {
    union { unsigned int i; float f; } v; v.i = ((unsigned int)u) << 16; return v.f;
}
__device__ __forceinline__ unsigned short f2b(float f) {
    union { float f; unsigned int i; } v; v.f = f;
    unsigned int i = v.i;
    i += 0x7fffu + ((i >> 16) & 1u);   // RNE (finite only)
    return (unsigned short)(i >> 16);
}

typedef __attribute__((ext_vector_type(8))) short bf16x8;
typedef __attribute__((ext_vector_type(4))) float f32x4;

__device__ __forceinline__ f32x4 mfma16(bf16x8 a, bf16x8 b, f32x4 c) {
    return __builtin_amdgcn_mfma_f32_16x16x32_bf16(a, b, c, 0, 0, 0);
}

// ---------------------------------------------------------------------------
// prep_x: fp32 x -> bf16 hi/lo split
// ---------------------------------------------------------------------------
__global__ __launch_bounds__(256) void prep_x(const float* __restrict__ x)
{
    const int i = (blockIdx.x * 256 + threadIdx.x) * 4;
    if (i >= NXEL_) return;
    const float4 v = *(const float4*)(x + i);
    ushort4 hi, lo;
    hi.x = f2b(v.x); lo.x = f2b(v.x - b2f(hi.x));
    hi.y = f2b(v.y); lo.y = f2b(v.y - b2f(hi.y));
    hi.z = f2b(v.z); lo.z = f2b(v.z - b2f(hi.z));
    hi.w = f2b(v.w); lo.w = f2b(v.w - b2f(hi.w));
    *(ushort4*)(g_xh + i) = hi;
    *(ushort4*)(g_xl + i) = lo;
}

// ---------------------------------------------------------------------------
// prep_w: attn-conv weights -> chunk-major [72][128][32] bf16 (hi/lo for
// w_theta/w_phi); conv_out weights -> chunk-major [36][256][32].
// ---------------------------------------------------------------------------
__global__ __launch_bounds__(256) void prep_w(
    const float* __restrict__ wt, const float* __restrict__ wp,
    const float* __restrict__ wg, const float* __restrict__ wc)
{
    const int i = blockIdx.x * 256 + threadIdx.x;
    if (i >= WEL_) return;
    {
        const int t  = i / (256 * 128);
        const int r  = i % (256 * 128);
        const int ci = r >> 7;
        const int f  = r & 127;
        const size_t d = (size_t)(t * 8 + (ci >> 5)) * 4096
                       + (size_t)f * 32 + (ci & 31);
        const float tv = wt[i];
        const unsigned short th = f2b(tv);
        g_wtTh[d] = th; g_wtTl[d] = f2b(tv - b2f(th));
        const float pv = wp[i];
        const unsigned short ph = f2b(pv);
        g_wpTh[d] = ph; g_wpTl[d] = f2b(pv - b2f(ph));
        g_wgT[d] = f2b(wg[i]);
    }
    {
        const int t  = i / (128 * 256);
        const int r  = i % (128 * 256);
        const int ci = r >> 8;
        const int f  = r & 255;
        const size_t d = (size_t)(t * 4 + (ci >> 5)) * 8192
                       + (size_t)f * 32 + (ci & 31);
        g_wcT[d] = f2b(wc[i]);
    }
}

// ---------------------------------------------------------------------------
// conv3_mfma v4 (verified r10): LDS-staged implicit-GEMM 3x3 conv, 3 heads
// fused, theta hi/lo pack fused into the epilogue.
// ---------------------------------------------------------------------------
__global__ __launch_bounds__(512) void conv3_mfma()
{
    __shared__ __align__(16) unsigned short w_lds[5][128][40];   // 50 KB
    __shared__ __align__(16) unsigned short x_lds[64][2][40];    // 10 KB

    const int tid  = threadIdx.x;
    const int wv   = tid >> 6;
    const int lane = tid & 63;
    const int quad = lane >> 4;
    const int ll   = lane & 15;
    const int wp   = wv >> 2;          // pixel group 0..1
    const int wf   = wv & 3;           // filter group 0..3
    const int P0   = blockIdx.x * 64;
    const int fb   = wf * 32;

    // staging thread maps
    const int sxp = tid >> 3;          // x: pixel 0..63
    const int sxh = (tid >> 2) & 1;    // x: hi/lo
    const int sxc = (tid & 3) * 8;     // x: ch offset
    const int swf = tid >> 2;          // w: filter 0..127
    const int swc = (tid & 3) * 8;     // w: ch offset

    // x staging source pixel coords
    const int sp  = P0 + sxp;
    const int spb = sp / NPIX_;
    const int spl = sp % NPIX_;
    const int sph = spl / WW_;
    const int spw = spl % WW_;

    const bf16x8 ZV = {0,0,0,0,0,0,0,0};
    bf16x8 rx, rw0, rw1, rw2, rw3, rw4;

#define C3_STAGE_LOAD(s)                                                      \
    {                                                                         \
        const int t_ = (s) >> 3, kc_ = (s) & 7;                               \
        const int hh_ = sph + t_ / 3 - 1, ww_ = spw + t_ % 3 - 1;             \
        if (hh_ >= 0 && hh_ < HH_ && ww_ >= 0 && ww_ < WW_) {                 \
            const size_t src_ = ((size_t)spb * NPIX_ + hh_ * WW_ + ww_) * CIN_\
                                + kc_ * 32 + sxc;                             \
            rx = sxh ? *(const bf16x8*)(g_xl + src_)                          \
                     : *(const bf16x8*)(g_xh + src_);                         \
        } else rx = ZV;                                                       \
        const size_t ws_ = (size_t)(s) * 4096 + (size_t)swf * 32 + swc;       \
        rw0 = *(const bf16x8*)(g_wtTh + ws_);                                 \
        rw1 = *(const bf16x8*)(g_wtTl + ws_);                                 \
        rw2 = *(const bf16x8*)(g_wpTh + ws_);                                 \
        rw3 = *(const bf16x8*)(g_wpTl + ws_);                                 \
        rw4 = *(const bf16x8*)(g_wgT  + ws_);                                 \
    }

#define C3_STAGE_WRITE()                                                      \
    {                                                                         \
        *(bf16x8*)(&x_lds[sxp][sxh][sxc]) = rx;                               \
        *(bf16x8*)(&w_lds[0][swf][swc]) = rw0;                                \
        *(bf16x8*)(&w_lds[1][swf][swc]) = rw1;                                \
        *(bf16x8*)(&w_lds[2][swf][swc]) = rw2;                                \
        *(bf16x8*)(&w_lds[3][swf][swc]) = rw3;                                \
        *(bf16x8*)(&w_lds[4][swf][swc]) = rw4;                                \
    }

    f32x4 aT[2][2], aP[2][2], aG[2][2];   // [pt][ft]
    #pragma unroll
    for (int pt = 0; pt < 2; ++pt)
        #pragma unroll
        for (int ft = 0; ft < 2; ++ft) {
            aT[pt][ft] = (f32x4){0.f,0.f,0.f,0.f};
            aP[pt][ft] = (f32x4){0.f,0.f,0.f,0.f};
            aG[pt][ft] = (f32x4){0.f,0.f,0.f,0.f};
        }

    C3_STAGE_LOAD(0);
    C3_STAGE_WRITE();
    __syncthreads();

    for (int s = 0; s < 72; ++s) {
        const bool pf = (s + 1 < 72);
        if (pf) C3_STAGE_LOAD(s + 1);

        bf16x8 xa[2][2];   // [pt][hi/lo]
        #pragma unroll
        for (int pt = 0; pt < 2; ++pt) {
            const int px = wp * 32 + pt * 16 + ll;
            xa[pt][0] = *(const bf16x8*)(&x_lds[px][0][quad * 8]);
            xa[pt][1] = *(const bf16x8*)(&x_lds[px][1][quad * 8]);
        }
        #pragma unroll
        for (int ft = 0; ft < 2; ++ft) {
            const int f = fb + ft * 16 + ll;
            const bf16x8 tH = *(const bf16x8*)(&w_lds[0][f][quad * 8]);
            const bf16x8 tL = *(const bf16x8*)(&w_lds[1][f][quad * 8]);
            const bf16x8 pH = *(const bf16x8*)(&w_lds[2][f][quad * 8]);
            const bf16x8 pL = *(const bf16x8*)(&w_lds[3][f][quad * 8]);
            const bf16x8 gB = *(const bf16x8*)(&w_lds[4][f][quad * 8]);
            #pragma unroll
            for (int pt = 0; pt < 2; ++pt) {
                aT[pt][ft] = mfma16(xa[pt][0], tH, aT[pt][ft]);
                aT[pt][ft] = mfma16(xa[pt][0], tL, aT[pt][ft]);
                aT[pt][ft] = mfma16(xa[pt][1], tH, aT[pt][ft]);
                aP[pt][ft] = mfma16(xa[pt][0], pH, aP[pt][ft]);
                aP[pt][ft] = mfma16(xa[pt][0], pL, aP[pt][ft]);
                aP[pt][ft] = mfma16(xa[pt][1], pH, aP[pt][ft]);
                aG[pt][ft] = mfma16(xa[pt][0], gB, aG[pt][ft]);
            }
        }

        __syncthreads();               // all reads of this tile done
        if (pf) C3_STAGE_WRITE();      // vmcnt wait folds in here
        __syncthreads();               // next tile visible
    }

    #pragma unroll
    for (int pt = 0; pt < 2; ++pt)
        #pragma unroll
        for (int ft = 0; ft < 2; ++ft) {
            const int f = fb + ft * 16 + ll;
            #pragma unroll
            for (int r = 0; r < 4; ++r) {
                const size_t n = P0 + wp * 32 + pt * 16 + quad * 4 + r;
                const float tv = aT[pt][ft][r];
                const unsigned short th = f2b(tv);
                g_th_hi[n * NF_ + f] = th;
                g_th_lo[n * NF_ + f] = f2b(tv - b2f(th));
                g_phi[n * NF_ + f] = aP[pt][ft][r];
                g_gv [n * NF_ + f] = aG[pt][ft][r];
            }
        }
#undef C3_STAGE_LOAD
#undef C3_STAGE_WRITE
}

// ---------------------------------------------------------------------------
// prep_tr_phi: LDS-tiled transpose of phi -> phT hi/lo. (verified r10)
// ---------------------------------------------------------------------------
__global__ __launch_bounds__(256) void prep_tr_phi()
{
    __shared__ float tile[128][65];    // 33.3 KB

    const int tid = threadIdx.x;
    const int b   = blockIdx.x & 1;
    const int mp0 = (blockIdx.x >> 1) * 64;
    const size_t boff = (size_t)b * (NPIX_ * NF_);

    // read: 128 cp-rows x 64 mp-cols, coalesced float4
    const int rr = tid >> 1;           // cp 0..127
    const int rc = (tid & 1) * 32;     // mp col group
    #pragma unroll
    for (int k = 0; k < 8; ++k) {
        const float4 v = *(const float4*)(
            g_phi + boff + (size_t)rr * NPIX_ + mp0 + rc + k * 4);
        tile[rr][rc + k * 4 + 0] = v.x;
        tile[rr][rc + k * 4 + 1] = v.y;
        tile[rr][rc + k * 4 + 2] = v.z;
        tile[rr][rc + k * 4 + 3] = v.w;
    }
    __syncthreads();

    // write: 64 mp-rows x 128 cp-cols
    const int ml = tid >> 2;           // mp local 0..63
    const int cg = (tid & 3) * 32;     // cp group
    __attribute__((aligned(16))) unsigned short hi[32], lo[32];
    #pragma unroll
    for (int k = 0; k < 32; ++k) {
        const float v = tile[cg + k][ml];
        hi[k] = f2b(v);
        lo[k] = f2b(v - b2f(hi[k]));
    }
    unsigned short* dh = g_phT_hi + boff + (size_t)(mp0 + ml) * NF_ + cg;
    unsigned short* dl = g_phT_lo + boff + (size_t)(mp0 + ml) * NF_ + cg;
    #pragma unroll
    for (int k = 0; k < 32; k += 8) {
        *(uint4*)(dh + k) = *(const uint4*)(hi + k);
        *(uint4*)(dl + k) = *(const uint4*)(lo + k);
    }
}

// ---------------------------------------------------------------------------
// prep_tr_g: LDS-tiled transpose of g -> gT. (verified r10)
// ---------------------------------------------------------------------------
__global__ __launch_bounds__(256) void prep_tr_g()
{
    __shared__ float tile[64][129];    // 33 KB

    const int tid = threadIdx.x;
    const int b   = blockIdx.x & 1;
    const int nl0 = (blockIdx.x >> 1) * 64;
    const size_t boff = (size_t)b * (NPIX_ * NF_);

    // read: 64 nl-rows x 128 c-cols, coalesced float4
    const int rn = tid >> 2;           // nl local 0..63
    const int rc = (tid & 3) * 32;     // c col group
    #pragma unroll
    for (int k = 0; k < 8; ++k) {
        const float4 v = *(const float4*)(
            g_gv + boff + (size_t)(nl0 + rn) * NF_ + rc + k * 4);
        tile[rn][rc + k * 4 + 0] = v.x;
        tile[rn][rc + k * 4 + 1] = v.y;
        tile[rn][rc + k * 4 + 2] = v.z;
        tile[rn][rc + k * 4 + 3] = v.w;
    }
    __syncthreads();

    // write: 128 c-rows x 64 nl-cols
    const int cl = tid >> 1;           // c local 0..127
    const int ng = (tid & 1) * 32;     // nl group
    __attribute__((aligned(16))) unsigned short gv[32];
    #pragma unroll
    for (int k = 0; k < 32; ++k)
        gv[k] = f2b(tile[ng + k][cl]);
    unsigned short* dst = g_gT + boff + (size_t)cl * NPIX_ + nl0 + ng;
    #pragma unroll
    for (int k = 0; k < 32; k += 8)
        *(uint4*)(dst + k) = *(const uint4*)(gv + k);
}

// ---------------------------------------------------------------------------
// attn_mfma v7 (verified r7/r9/r10: 149-152us) — FINAL. Flash-style,
// LDS-staged KV, swapped QK^T in-register softmax, cvt_pk P-pack,
// defer-rescale.
//
// Operating point is a verified local optimum on all three resource axes:
//  - v8 (32x32 MFMA, half LDS traffic): regs 84->204 -> occupancy 8.9%, 184us
//  - v9 (double-buffer, half barriers):  LDS 32->60KB -> occupancy 19%, 161us
//  - v10 (K XOR-swizzle):               conflicts UNCHANGED (1.984e7 is
//    layout-invariant: with 16 ll x 4 quad b128 reads, bank-group =
//    ((4kk+q)&7)^(ll&7) still lands 8 lanes/group; the XOR only permutes
//    within-ll), and per-lane addresses defeated immediate-offset
//    addressing -> 169us. The counted conflicts are a structural floor of
//    this read shape.
// ---------------------------------------------------------------------------
__global__ __launch_bounds__(256) void attn_mfma()
{
    __shared__ __align__(16) unsigned short kh_lds[KVB_][136];  // 8.7 KB
    __shared__ __align__(16) unsigned short kl_lds[KVB_][136];  // 8.7 KB
    __shared__ __align__(16) unsigned short v_lds[NF_][40];     // 10 KB
    // per-wave: cols 0..31 = P rows [q][m]; cols 32..39 of rows 0..3 = al[16]
    __shared__ __align__(16) short p_lds[4][16 * 40];           // 5.1 KB

    const int tid  = threadIdx.x;
    const int w    = tid >> 6;
    const int lane = tid & 63;
    const int quad = lane >> 4;
    const int ll   = lane & 15;

    const int cid = blockIdx.x & 15;        // (b,kvs): round-robin over XCDs
    const int qw  = blockIdx.x >> 4;        // 0..99
    const int b   = cid >> 3;
    const int kvs = cid & 7;
    const int R0  = b * NPIX_ + qw * 64;    // 64 Q rows per block
    const int m_start = kvs * MCHUNK_;      // within-batch m offset

    const unsigned short* phH = g_phT_hi + (size_t)b * (NPIX_ * NF_);
    const unsigned short* phL = g_phT_lo + (size_t)b * (NPIX_ * NF_);
    const unsigned short* gT  = g_gT    + (size_t)b * (NPIX_ * NF_);

    // theta fragments for this wave's 16 rows (B operand: col q=ll)
    bf16x8 aH[4], aL[4];
    #pragma unroll
    for (int kk = 0; kk < 4; ++kk) {
        const size_t off = (size_t)(R0 + w * 16 + ll) * 128 + kk * 32 + quad * 8;
        aH[kk] = *(const bf16x8*)(g_th_hi + off);
        aL[kk] = *(const bf16x8*)(g_th_lo + off);
    }

    f32x4 acc[8];
    #pragma unroll
    for (int t = 0; t < 8; ++t) acc[t] = (f32x4){0.f, 0.f, 0.f, 0.f};
    float mi = -1e30f, li = 0.f;            // per-lane: q = ll

    const int kr0 = tid >> 4;            // K rows 0..15 (and +16)
    const int kc0 = (tid & 15) * 8;      // K col elems
    const int vr0 = tid >> 2;            // V rows 0..63 (and +64)
    const int vm0 = (tid & 3) * 8;       // V m elems

    bf16x8 skh0, skh1, skl0, skl1, sv0, sv1;

    {
        const int m0 = m_start;
        skh0 = *(const bf16x8*)(phH + (size_t)(m0 + kr0) * 128 + kc0);
        skh1 = *(const bf16x8*)(phH + (size_t)(m0 + kr0 + 16) * 128 + kc0);
        skl0 = *(const bf16x8*)(phL + (size_t)(m0 + kr0) * 128 + kc0);
        skl1 = *(const bf16x8*)(phL + (size_t)(m0 + kr0 + 16) * 128 + kc0);
        sv0  = *(const bf16x8*)(gT + (size_t)vr0 * NPIX_ + m0 + vm0);
        sv1  = *(const bf16x8*)(gT + (size_t)(vr0 + 64) * NPIX_ + m0 + vm0);
        *(bf16x8*)(&kh_lds[kr0][kc0])      = skh0;
        *(bf16x8*)(&kh_lds[kr0 + 16][kc0]) = skh1;
        *(bf16x8*)(&kl_lds[kr0][kc0])      = skl0;
        *(bf16x8*)(&kl_lds[kr0 + 16][kc0]) = skl1;
        *(bf16x8*)(&v_lds[vr0][vm0])       = sv0;
        *(bf16x8*)(&v_lds[vr0 + 64][vm0])  = sv1;
    }
    __syncthreads();

    short* pl = &p_lds[w][0];

    for (int it = 0; it < NIT_; ++it) {
        const bool pf = (it + 1 < NIT_);
        if (pf) {
            const int m0 = m_start + (it + 1) * KVB_;
            skh0 = *(const bf16x8*)(phH + (size_t)(m0 + kr0) * 128 + kc0);
            skh1 = *(const bf16x8*)(phH + (size_t)(m0 + kr0 + 16) * 128 + kc0);
            skl0 = *(const bf16x8*)(phL + (size_t)(m0 + kr0) * 128 + kc0);
            skl1 = *(const bf16x8*)(phL + (size_t)(m0 + kr0 + 16) * 128 + kc0);
            sv0  = *(const bf16x8*)(gT + (size_t)vr0 * NPIX_ + m0 + vm0);
            sv1  = *(const bf16x8*)(gT + (size_t)(vr0 + 64) * NPIX_ + m0 + vm0);
        }

        // ---- S = K * theta^T (swapped): s[mt][r] = S[m=mt*16+quad*4+r][q=ll]
        f32x4 s[2];
        #pragma unroll
        for (int mt = 0; mt < 2; ++mt) {
            f32x4 s0 = (f32x4){0.f,0.f,0.f,0.f};
            const int mrow = mt * 16 + ll;
            #pragma unroll
            for (int kk = 0; kk < 4; ++kk) {
                const bf16x8 bH = *(const bf16x8*)(&kh_lds[mrow][kk * 32 + quad * 8]);
                const bf16x8 bL = *(const bf16x8*)(&kl_lds[mrow][kk * 32 + quad * 8]);
                s0 = mfma16(bH, aH[kk], s0);
                s0 = mfma16(bL, aH[kk], s0);
                s0 = mfma16(bH, aL[kk], s0);
            }
            s[mt] = s0;
        }

        // ---- per-lane online softmax for q = ll ---------------------------
        float cm = fmaxf(fmaxf(fmaxf(s[0][0], s[0][1]), fmaxf(s[0][2], s[0][3])),
                         fmaxf(fmaxf(s[1][0], s[1][1]), fmaxf(s[1][2], s[1][3])));
        cm = fmaxf(cm, __shfl_xor(cm, 16));
        cm = fmaxf(cm, __shfl_xor(cm, 32));
        // defer-rescale (T13): wave-uniform skip when no q-row grows > THR
        const bool nog = __all(cm <= mi + 4.0f);
        if (!nog) {
            const float nm = fmaxf(mi, cm);
            const float al = __expf(mi - nm);
            mi = nm;
            li *= al;
            if (quad == 0)
                ((float*)(pl + (ll >> 2) * 40 + 32))[ll & 3] = al;
        }
        float ssum = 0.f;
        #pragma unroll
        for (int mt = 0; mt < 2; ++mt)
            #pragma unroll
            for (int r = 0; r < 4; ++r) {
                const float e = __expf(s[mt][r] - mi);
                s[mt][r] = e; ssum += e;
            }
        ssum += __shfl_xor(ssum, 16);
        ssum += __shfl_xor(ssum, 32);
        li += ssum;

        // ---- P pack via v_cvt_pk_bf16_f32 (T12): 2 uint stores ------------
        #pragma unroll
        for (int mt = 0; mt < 2; ++mt) {
            unsigned int c0_, c1_;
            asm("v_cvt_pk_bf16_f32 %0, %1, %2"
                : "=v"(c0_) : "v"(s[mt][0]), "v"(s[mt][1]));
            asm("v_cvt_pk_bf16_f32 %0, %1, %2"
                : "=v"(c1_) : "v"(s[mt][2]), "v"(s[mt][3]));
            *(uint2*)(pl + ll * 40 + mt * 16 + quad * 4) = make_uint2(c0_, c1_);
        }

        // ---- rescale acc rows with their al (skipped when deferred) -------
        if (!nog) {
            const float* alp = (const float*)(pl + quad * 40 + 32);
            #pragma unroll
            for (int r = 0; r < 4; ++r) {
                const float av = alp[r];
                #pragma unroll
                for (int t = 0; t < 8; ++t) acc[t][r] *= av;
            }
        }

        const bf16x8 pa = *(const bf16x8*)(pl + ll * 40 + quad * 8);

        // ---- PV: 8 channel-tiles, k=32 ------------------------------------
        #pragma unroll
        for (int ct = 0; ct < 8; ++ct) {
            const bf16x8 gb = *(const bf16x8*)(&v_lds[ct * 16 + ll][quad * 8]);
            acc[ct] = mfma16(pa, gb, acc[ct]);
        }

        __syncthreads();
        if (pf) {
            *(bf16x8*)(&kh_lds[kr0][kc0])      = skh0;
            *(bf16x8*)(&kh_lds[kr0 + 16][kc0]) = skh1;
            *(bf16x8*)(&kl_lds[kr0][kc0])      = skl0;
            *(bf16x8*)(&kl_lds[kr0 + 16][kc0]) = skl1;
            *(bf16x8*)(&v_lds[vr0][vm0])       = sv0;
            *(bf16x8*)(&v_lds[vr0 + 64][vm0])  = sv1;
        }
        __syncthreads();
    }

    const int row0 = R0 + w * 16;
    #pragma unroll
    for (int ct = 0; ct < 8; ++ct)
        #pragma unroll
        for (int r = 0; r < 4; ++r)
            g_po[((size_t)kvs * NTOK_ + row0 + quad * 4 + r) * NF_ + ct * 16 + ll]
                = acc[ct][r];
    if (quad == 0) {
        const size_t mlidx = ((size_t)kvs * NTOK_ + row0 + ll) * 2;
        g_pml[mlidx]     = mi;
        g_pml[mlidx + 1] = li;
    }
}

// ---------------------------------------------------------------------------
// merge_attn: combine KVS_ fp32 partials -> normalized bf16 g_aob
// ---------------------------------------------------------------------------
__global__ __launch_bounds__(256) void merge_attn()
{
    const int idx = blockIdx.x * 256 + threadIdx.x;   // NTOK_*16 threads
    const int row = idx >> 4;
    const int c0  = (idx & 15) * 8;

    float m[KVS_], l[KVS_];
    #pragma unroll
    for (int s = 0; s < KVS_; ++s) {
        const size_t mlidx = ((size_t)s * NTOK_ + row) * 2;
        m[s] = g_pml[mlidx];
        l[s] = g_pml[mlidx + 1];
    }
    float M = m[0];
    #pragma unroll
    for (int s = 1; s < KVS_; ++s) M = fmaxf(M, m[s]);
    float a[KVS_], L = 0.f;
    #pragma unroll
    for (int s = 0; s < KVS_; ++s) {
        a[s] = __expf(m[s] - M);
        L += a[s] * l[s];
    }
    const float inv = 1.f / L;

    float o[8];
    #pragma unroll
    for (int j = 0; j < 8; ++j) o[j] = 0.f;
    #pragma unroll
    for (int s = 0; s < KVS_; ++s) {
        const float* p = g_po + ((size_t)s * NTOK_ + row) * NF_ + c0;
        const float4 p0 = *(const float4*)(p);
        const float4 p1 = *(const float4*)(p + 4);
        o[0] += a[s] * p0.x; o[1] += a[s] * p0.y;
        o[2] += a[s] * p0.z; o[3] += a[s] * p0.w;
        o[4] += a[s] * p1.x; o[5] += a[s] * p1.y;
        o[6] += a[s] * p1.z; o[7] += a[s] * p1.w;
    }
    unsigned short tmp[8];
    #pragma unroll
    for (int j = 0; j < 8; ++j) tmp[j] = f2b(o[j] * inv);
    unsigned short* dst = g_aob + (size_t)row * NF_ + c0;
    *(ushort4*)(dst)     = make_ushort4(tmp[0], tmp[1], tmp[2], tmp[3]);
    *(ushort4*)(dst + 4) = make_ushort4(tmp[4], tmp[5], tmp[6], tmp[7]);
}

// ---------------------------------------------------------------------------
// conv_out_mfma v3 (verified r11): LDS-staged implicit-GEMM 3x3 conv +
// fp32 residual, double-buffered (one barrier/step). Grid 200 = 1 block/CU
// -> LDS growth free; worth ~3.6us vs v2 (r10/r11 non-attn decomposition).
// ---------------------------------------------------------------------------
__global__ __launch_bounds__(512) void conv_out_mfma(
    const float* __restrict__ x, float* __restrict__ out)
{
    __shared__ __align__(16) unsigned short w_lds[2][256][40];   // 40 KB
    __shared__ __align__(16) unsigned short a_lds[2][64][40];    // 10 KB

    const int tid  = threadIdx.x;
    const int wv   = tid >> 6;
    const int lane = tid & 63;
    const int quad = lane >> 4;
    const int ll   = lane & 15;
    const int wp   = wv >> 2;            // pixel group 0..1
    const int wf   = wv & 3;             // filter group 0..3 (64 f each)
    const int P0   = blockIdx.x * 64;
    const int fb   = wf * 64;

    const int swf = tid >> 1;            // W: filter 0..255
    const int swc = (tid & 1) * 16;      // W: ch offset 0/16
    const int sap = tid >> 2;            // A: pixel idx (valid when tid<256)
    const int sac = (tid & 3) * 8;       // A: ch offset

    const int sp  = P0 + sap;
    const int spb = sp / NPIX_;
    const int spl = sp % NPIX_;
    const int sph = spl / WW_;
    const int spw = spl % WW_;

    const bf16x8 ZV = {0,0,0,0,0,0,0,0};
    bf16x8 ra, rwA, rwB;

#define CO_STAGE_LOAD(s)                                                      \
    {                                                                         \
        const int t_ = (s) >> 2, kc_ = (s) & 3;                               \
        if (tid < 256) {                                                      \
            const int hh_ = sph + t_ / 3 - 1, ww_ = spw + t_ % 3 - 1;         \
            if (hh_ >= 0 && hh_ < HH_ && ww_ >= 0 && ww_ < WW_) {             \
                const size_t src_ = ((size_t)spb * NPIX_ + hh_ * WW_ + ww_)   \
                                    * NF_ + kc_ * 32 + sac;                   \
                ra = *(const bf16x8*)(g_aob + src_);                          \
            } else ra = ZV;                                                   \
        }                                                                     \
        const size_t ws_ = (size_t)(s) * 8192 + (size_t)swf * 32 + swc;       \
        rwA = *(const bf16x8*)(g_wcT + ws_);                                  \
        rwB = *(const bf16x8*)(g_wcT + ws_ + 8);                              \
    }

#define CO_STAGE_WRITE(bi)                                                    \
    {                                                                         \
        if (tid < 256) *(bf16x8*)(&a_lds[bi][sap][sac]) = ra;                 \
        *(bf16x8*)(&w_lds[bi][swf][swc])     = rwA;                           \
        *(bf16x8*)(&w_lds[bi][swf][swc + 8]) = rwB;                           \
    }

    f32x4 acc[2][4];
    #pragma unroll
    for (int pt = 0; pt < 2; ++pt)
        #pragma unroll
        for (int ft = 0; ft < 4; ++ft) acc[pt][ft] = (f32x4){0.f,0.f,0.f,0.f};

    CO_STAGE_LOAD(0);
    CO_STAGE_WRITE(0);
    __syncthreads();

    int cur = 0;
    for (int s = 0; s < 36; ++s) {
        const bool pf = (s + 1 < 36);
        if (pf) CO_STAGE_LOAD(s + 1);

        bf16x8 a[2];
        #pragma unroll
        for (int pt = 0; pt < 2; ++pt)
            a[pt] = *(const bf16x8*)(&a_lds[cur][wp * 32 + pt * 16 + ll][quad * 8]);
        #pragma unroll
        for (int ft = 0; ft < 4; ++ft) {
            const bf16x8 bw = *(const bf16x8*)(&w_lds[cur][fb + ft * 16 + ll][quad * 8]);
            #pragma unroll
            for (int pt = 0; pt < 2; ++pt)
                acc[pt][ft] = mfma16(a[pt], bw, acc[pt][ft]);
        }

        if (pf) CO_STAGE_WRITE(cur ^ 1);
        __syncthreads();
        cur ^= 1;
    }

    #pragma unroll
    for (int pt = 0; pt < 2; ++pt)
        #pragma unroll
        for (int ft = 0; ft < 4; ++ft) {
            const int f = fb + ft * 16 + ll;
            #pragma unroll
            for (int r = 0; r < 4; ++r) {
                const size_t n = P0 + wp * 32 + pt * 16 + quad * 4 + r;
                const size_t oi = n * CIN_ + f;
                out[oi] = x[oi] + acc[pt][ft][r];
            }
        }
#undef CO_STAGE_LOAD
#undef CO_STAGE_WRITE
}

// ---------------------------------------------------------------------------
extern "C" void kernel_launch(void* const* d_in, const int* in_sizes, int n_in,
                              void* d_out, int out_size, void* d_ws, size_t ws_size,
                              hipStream_t stream)
{
    const float* x  = (const float*)d_in[0];
    const float* wt = (const float*)d_in[1];
    const float* wp = (const float*)d_in[2];
    const float* wg = (const float*)d_in[3];
    const float* wc = (const float*)d_in[4];
    float* out = (float*)d_out;

    prep_x<<<NXEL_ / 4 / 256, 256, 0, stream>>>(x);
    prep_w<<<(WEL_ + 255) / 256, 256, 0, stream>>>(wt, wp, wg, wc);
    conv3_mfma<<<NTOK_ / 64, 512, 0, stream>>>();
    prep_tr_phi<<<2 * (NPIX_ / 64), 256, 0, stream>>>();
    prep_tr_g<<<2 * (NPIX_ / 64), 256, 0, stream>>>();
    attn_mfma<<<(NTOK_ / 64) * KVS_, 256, 0, stream>>>();
    merge_attn<<<NTOK_ * 16 / 256, 256, 0, stream>>>();
    conv_out_mfma<<<NTOK_ / 64, 512, 0, stream>>>(x, out);
}